// Round 3
// baseline (462.482 us; speedup 1.0000x reference)
//
#include <hip/hip_runtime.h>

#define NN 100000
#define NE 1200000
#define DD 64
#define EPSV 1e-7f
#define NGROUPS (NN / 4)        // 25000 groups of 4 nodes; exact (NN % 4 == 0)
#define GRID_BLOCKS 2048        // persistent: 2x oversubscription of 1024 resident

// Native 4-float vector for __builtin_nontemporal_load (HIP float4 is a class
// type the builtin rejects; clang ext_vector_type is accepted).
typedef float nfloat4 __attribute__((ext_vector_type(4)));

// Kernel A: CSR offsets. off[n] = lower_bound(dst, n) for sorted dst; off[NN]=NE.
// Poison-safe: every off[] slot is rewritten each launch.
__global__ __launch_bounds__(256)
void build_offsets(const int* __restrict__ dst, int* __restrict__ off) {
    int i = blockIdx.x * 256 + threadIdx.x;
    if (i >= NE) return;
    int d = dst[i];
    int prev = (i == 0) ? -1 : dst[i - 1];
    for (int n = prev + 1; n <= d; ++n) off[n] = i;
    if (i == NE - 1) {
        for (int n = d + 1; n <= NN; ++n) off[n] = NE;
    }
}

// Batched edge round: NB*4 edges starting at base, exec-masked against ee.
// All src+ef loads issue together, then all nf gathers -> 2 serial round trips.
template<int NB>
__device__ __forceinline__ void edge_round(int base, int ee, int eg, int cg,
                                           const int* __restrict__ src,
                                           const nfloat4* __restrict__ ef4,
                                           const float4* __restrict__ nf4,
                                           float* sp, float* wp)
{
    int     sk[NB];
    nfloat4 efv[NB];
    bool    okv[NB];
    #pragma unroll
    for (int u = 0; u < NB; ++u) {
        int i = base + u * 4 + eg;
        bool ok = i < ee;
        okv[u] = ok;
        int ic = ok ? i : base;                  // clamp stays in-segment
        sk[u]  = src[ic];
        efv[u] = __builtin_nontemporal_load(&ef4[(size_t)ic * 16 + cg]);
    }
    float4 nfv[NB];
    #pragma unroll
    for (int u = 0; u < NB; ++u)
        nfv[u] = nf4[(size_t)sk[u] * 16 + cg];   // NB gathers in flight
    #pragma unroll
    for (int u = 0; u < NB; ++u) {
        const float* np = (const float*)&nfv[u];
        #pragma unroll
        for (int t = 0; t < 4; ++t) {
            float v = fmaxf(np[t] + efv[u][t], 0.f) + EPSV;
            float e = okv[u] ? __expf(v) : 0.f;
            sp[t] += e;
            wp[t] += e * v;
        }
    }
}

// Persistent-grid version (r6):
//  - 2048 blocks grid-stride over the 25000 node-groups: W^T staged in LDS
//    ONCE per block (was once per group: 400MB -> 33MB of W traffic, and
//    ~100M fewer VMEM instructions). b[lane]/scale hoisted likewise.
//  - Next group's off[n]/off[n+1]/h[n] loads issue BEFORE processing the
//    current group: the segment-lookup latency hides under exp/GEMV work.
//  - Degree-adaptive round-1: deg<=8 takes an 8-slot batch (wave-uniform
//    branch), deg<=16 a 16-slot batch, rare overflow loops by 8.
__global__ __launch_bounds__(256, 4)
void genconv_kernel(const float* __restrict__ node_feats,
                    const float* __restrict__ edge_feats,
                    const float* __restrict__ W,
                    const float* __restrict__ b,
                    const float* __restrict__ scale,
                    const int* __restrict__ src,
                    const int* __restrict__ dst,
                    const int* __restrict__ off,   // may be null -> bin search
                    float* __restrict__ out)
{
    // W^T in LDS, stride 65: read banks (d+lane)%32 -> 2-way aliasing (free).
    __shared__ float Wt[64 * 65];
    __shared__ float featL[4 * 64];      // per-wave feat staging for GEMV
    const int tid = threadIdx.x;

    #pragma unroll
    for (int r = 0; r < 16; ++r) {
        int idx = r * 256 + tid;
        Wt[(idx & 63) * 65 + (idx >> 6)] = W[idx];
    }

    const int wave = tid >> 6;
    const int lane = tid & 63;
    const int eg = lane >> 4;            // edge subgroup 0..3
    const int cg = lane & 15;            // channel group: channels cg*4..cg*4+3
    const float4*  nf4 = (const float4*)node_feats;
    const nfloat4* ef4 = (const nfloat4*)edge_feats;
    const float bl = b[lane];            // hoisted: constant across groups
    const float sc = scale[0];

    __syncthreads();                     // Wt visible before first GEMV

    int g = blockIdx.x;
    if (g >= NGROUPS) return;

    // Segment lookup for the first group.
    int n = g * 4 + wave;
    int es, ee;
    if (off) { es = off[n]; ee = off[n + 1]; }
    else {
        int target = (lane < 32) ? n : (n + 1);
        int lo = 0, hi = NE;
        while (lo < hi) { int mid = (lo + hi) >> 1;
                          if (dst[mid] < target) lo = mid + 1; else hi = mid; }
        es = __shfl(lo, 0, 64); ee = __shfl(lo, 32, 64);
    }
    float4 h4 = nf4[(size_t)n * 16 + cg];

    while (true) {
        // ---- prefetch next group's segment + h (hidden under this group) ----
        const int gn = g + gridDim.x;
        const bool have_next = gn < NGROUPS;
        int es_n = 0, ee_n = 0;
        float4 h4_n = {0.f, 0.f, 0.f, 0.f};
        if (have_next) {
            int n2 = gn * 4 + wave;
            if (off) { es_n = off[n2]; ee_n = off[n2 + 1]; }
            else {
                int target = (lane < 32) ? n2 : (n2 + 1);
                int lo = 0, hi = NE;
                while (lo < hi) { int mid = (lo + hi) >> 1;
                                  if (dst[mid] < target) lo = mid + 1; else hi = mid; }
                es_n = __shfl(lo, 0, 64); ee_n = __shfl(lo, 32, 64);
            }
            h4_n = nf4[(size_t)n2 * 16 + cg];
        }

        // ---- max-free softmax-weighted mean: agg = sum(v e^v)/sum(e^v) ----
        float4 ssum = {0.f, 0.f, 0.f, 0.f};
        float4 wsum = {0.f, 0.f, 0.f, 0.f};
        float* sp = (float*)&ssum;
        float* wp = (float*)&wsum;
        const int deg = ee - es;

        if (deg > 0) {
            if (deg <= 8) {                              // ~16% of nodes
                edge_round<2>(es, ee, eg, cg, src, ef4, nf4, sp, wp);
            } else {                                     // 16-slot main round
                edge_round<4>(es, ee, eg, cg, src, ef4, nf4, sp, wp);
                for (int base = es + 16; base < ee; base += 8)   // deg>16 tail
                    edge_round<2>(base, ee, eg, cg, src, ef4, nf4, sp, wp);
            }
        }

        // Reduce the 4 edge-subgroups (lanes L, L^16, L^32 hold same channels).
        float4 agg;
        float* ap = (float*)&agg;
        #pragma unroll
        for (int t = 0; t < 4; ++t) {
            sp[t] += __shfl_xor(sp[t], 16, 64);
            sp[t] += __shfl_xor(sp[t], 32, 64);
            wp[t] += __shfl_xor(wp[t], 16, 64);
            wp[t] += __shfl_xor(wp[t], 32, 64);
            ap[t] = (sp[t] > 0.f) ? (wp[t] / sp[t]) : 0.f;   // empty segment -> 0
        }

        // MessageNorm: feat = h + agg * (||h|| * scale / max(||agg||,1e-12))
        float* hp = (float*)&h4;
        float a2 = ap[0]*ap[0] + ap[1]*ap[1] + ap[2]*ap[2] + ap[3]*ap[3];
        float h2 = hp[0]*hp[0] + hp[1]*hp[1] + hp[2]*hp[2] + hp[3]*hp[3];
        #pragma unroll
        for (int o = 8; o >= 1; o >>= 1) {   // sum across the 16 channel groups
            a2 += __shfl_xor(a2, o, 64);
            h2 += __shfl_xor(h2, o, 64);
        }
        float k = sqrtf(h2) * sc / fmaxf(sqrtf(a2), 1e-12f);

        float4 feat;
        float* fp = (float*)&feat;
        #pragma unroll
        for (int t = 0; t < 4; ++t) fp[t] = hp[t] + ap[t] * k;

        // Stage feat in per-wave LDS (wave-synchronous; no barrier needed:
        // featL slot is private to this wave, Wt already synced once).
        if (eg == 0) *(float4*)&featL[wave * 64 + cg * 4] = feat;

        // GEMV: out[lane] = b[lane] + sum_d feat[d] * Wt[d][lane].
        float acc = bl;
        #pragma unroll
        for (int c4 = 0; c4 < 16; ++c4) {
            float4 f = *(const float4*)&featL[wave * 64 + c4 * 4];
            const float* fq = (const float*)&f;
            #pragma unroll
            for (int t = 0; t < 4; ++t)
                acc = fmaf(fq[t], Wt[(c4 * 4 + t) * 65 + lane], acc);
        }
        __builtin_nontemporal_store(acc, &out[(size_t)n * DD + lane]);

        if (!have_next) break;
        g = gn; n = gn * 4 + wave; es = es_n; ee = ee_n; h4 = h4_n;
    }
}

extern "C" void kernel_launch(void* const* d_in, const int* in_sizes, int n_in,
                              void* d_out, int out_size, void* d_ws, size_t ws_size,
                              hipStream_t stream) {
    const float* node_feats = (const float*)d_in[0];
    const float* edge_feats = (const float*)d_in[1];
    const float* W          = (const float*)d_in[2];
    const float* b          = (const float*)d_in[3];
    const float* scale      = (const float*)d_in[4];
    const int*   src        = (const int*)d_in[5];
    const int*   dst        = (const int*)d_in[6];
    float*       out        = (float*)d_out;

    int* off = nullptr;
    if (ws_size >= (size_t)(NN + 1) * sizeof(int)) {
        off = (int*)d_ws;
        build_offsets<<<(NE + 255) / 256, 256, 0, stream>>>(dst, off);
    }
    const int blocks = (GRID_BLOCKS < NGROUPS) ? GRID_BLOCKS : NGROUPS;
    genconv_kernel<<<blocks, 256, 0, stream>>>(node_feats, edge_feats, W, b,
                                               scale, src, dst, off, out);
}